// Round 1
// baseline (71.955 us; speedup 1.0000x reference)
//
#include <hip/hip_runtime.h>

#define SL 10
#define NI 128

typedef float f32x4 __attribute__((ext_vector_type(4)));
typedef unsigned int u32;
typedef u32 u32x4 __attribute__((ext_vector_type(4)));
typedef __bf16 bfrag __attribute__((ext_vector_type(8)));   // 8 bf16 = 4 VGPR MFMA frag
typedef _Float16 f16x4 __attribute__((ext_vector_type(4)));

__device__ __forceinline__ u32 fb(float f){ return __float_as_uint(f); }
__device__ __forceinline__ float hi32(float f){ return __uint_as_float(fb(f)&0xFFFF0000u); }

__device__ __forceinline__ f32x4 MF(bfrag a, bfrag b, f32x4 c){
  return __builtin_amdgcn_mfma_f32_16x16x32_bf16(a, b, c, 0, 0, 0);
}

__device__ __forceinline__ float sigf(float x){ return __fdividef(1.f, 1.f + __expf(-x)); }
__device__ __forceinline__ float tanhf2(float x){ return __fdividef(2.f, 1.f + __expf(-2.f*x)) - 1.f; }

// split 8 fp32 -> bf16-hi (truncated) and bf16-lo (residual) packed as 4 u32 each
__device__ __forceinline__ void pack8(float4 a, float4 b, u32x4& hi, u32x4& lo){
  float f[8] = {a.x,a.y,a.z,a.w,b.x,b.y,b.z,b.w};
  #pragma unroll
  for(int j=0;j<4;j++){
    float p=f[2*j], q=f[2*j+1];
    hi[j] = (fb(p)>>16) | (fb(q)&0xFFFF0000u);
    float pr = p - hi32(p), qr = q - hi32(q);
    lo[j] = (fb(pr)>>16) | (fb(qr)&0xFFFF0000u);
  }
}
__device__ __forceinline__ void pack8hi(float4 a, float4 b, u32x4& hi){
  float f[8] = {a.x,a.y,a.z,a.w,b.x,b.y,b.z,b.w};
  #pragma unroll
  for(int j=0;j<4;j++)
    hi[j] = (fb(f[2*j])>>16) | (fb(f[2*j+1])&0xFFFF0000u);
}

// LDS layout (bytes):
//  XH [64][136] bf16 : 0      .. 17408   (x hi-split, padded stride, 16B-aligned rows)
//  XL [64][136] bf16 : 17408  .. 34816   (x lo-split)
//  WL [20][64][16B]  : 34816  .. 55296   (W_ih lo-split frags; reused for W_ih_b hi)
//  XP [64][88]  f16  : 55296  .. 66560   (gate pre-acts, unit-major: col = unit*4+type)
//  HB [64][36]  u32  : 66560  .. 75776   (h packed (hh16<<16)|hl16, k-pad zeroed)
__global__ __launch_bounds__(256, 2) void bilstm_kernel(
    const float* __restrict__ x,
    const float* __restrict__ Wih_f, const float* __restrict__ Whh_f,
    const float* __restrict__ bih_f, const float* __restrict__ bhh_f,
    const float* __restrict__ Wih_b,
    const float* __restrict__ bih_b, const float* __restrict__ bhh_b,
    float* __restrict__ out)
{
  __shared__ __attribute__((aligned(16))) u32 smem[18944]; // 75776 B

  unsigned short* XH = (unsigned short*)smem;
  unsigned short* XL = XH + 64*136;
  u32*            WLp = smem + (34816>>2);
  _Float16*       XP  = (_Float16*)(smem + (55296>>2));
  u32*            HB  = smem + (66560>>2);

  const int tid  = threadIdx.x;
  const int lane = tid & 63;
  const int w    = tid >> 6;     // wave id = m-tile
  const int lr   = lane & 15;    // A-row / B-col index
  const int lg   = lane >> 4;    // k-group
  const int b0   = blockIdx.x << 6;
  const int srow = tid >> 2;     // staging/gate row (0..63)
  const int sseg = tid & 3;      // staging segment / unit group

  for(int i=tid;i<64*36;i+=256) HB[i]=0;   // zero h-buf incl. k-padding

  // ---- W_ih_f frags: hi in regs (all waves), lo staged to LDS ----
  bfrag WHF[20];
  #pragma unroll
  for(int p=0;p<20;p++){
    const int nt=p>>2, ks=p&3;
    const float* src = Wih_f + (nt*16+lr)*NI + ks*32 + lg*8;
    float4 a = *(const float4*)src;
    float4 b = *(const float4*)(src+4);
    u32x4 hi, lo;
    pack8(a,b,hi,lo);
    WHF[p] = __builtin_bit_cast(bfrag, hi);
    if(w == (p&3)) *(u32x4*)(WLp + p*256 + lane*4) = lo;
  }

  // ---- W_hh_f frags (K=20 zero-padded to 32), 2-level split, in regs ----
  bfrag W2H[5], W2L[5];
  #pragma unroll
  for(int nt=0;nt<5;nt++){
    u32x4 hi, lo;
    #pragma unroll
    for(int j=0;j<4;j++){
      const int k0 = lg*8 + 2*j;
      float p = (k0   < 20) ? Whh_f[(nt*16+lr)*20 + k0  ] : 0.f;
      float q = (k0+1 < 20) ? Whh_f[(nt*16+lr)*20 + k0+1] : 0.f;
      hi[j] = (fb(p)>>16) | (fb(q)&0xFFFF0000u);
      float pr = p - hi32(p), qr = q - hi32(q);
      lo[j] = (fb(pr)>>16) | (fb(qr)&0xFFFF0000u);
    }
    W2H[nt] = __builtin_bit_cast(bfrag, hi);
    W2L[nt] = __builtin_bit_cast(bfrag, lo);
  }

  float biasf[5];
  #pragma unroll
  for(int nt=0;nt<5;nt++) biasf[nt] = bih_f[nt*16+lr] + bhh_f[nt*16+lr];

  int colp[5];  // unit-major xp column for this lane's C-frag col
  #pragma unroll
  for(int nt=0;nt<5;nt++){ int g=nt*16+lr; colp[nt] = (g%20)*4 + g/20; }

  // prefetch x tile t=0 into regs
  float4 xs[8];
  {
    const float* p = x + ((long)(b0+srow)*SL + 0)*NI + sseg*32;
    #pragma unroll
    for(int i=0;i<8;i++) xs[i] = ((const float4*)p)[i];
  }

  float cst[5];
  #pragma unroll
  for(int u=0;u<5;u++) cst[u]=0.f;

  f32x4 acc[5];

  __syncthreads();

  for(int t=0;t<SL;t++){
    // ---------- phase A: bias init + h-recurrence MFMA + stage x_t ----------
    #pragma unroll
    for(int nt=0;nt<5;nt++){ f32x4 v = {biasf[nt],biasf[nt],biasf[nt],biasf[nt]}; acc[nt]=v; }
    if(t>0){
      const u32* hp = HB + (w*16+lr)*36 + lg*8;
      u32x4 h0 = *(const u32x4*)hp;
      u32x4 h1 = *(const u32x4*)(hp+4);
      u32x4 hh, hl;
      hh[0] = (h0[0]>>16) | (h0[1]&0xFFFF0000u);
      hh[1] = (h0[2]>>16) | (h0[3]&0xFFFF0000u);
      hh[2] = (h1[0]>>16) | (h1[1]&0xFFFF0000u);
      hh[3] = (h1[2]>>16) | (h1[3]&0xFFFF0000u);
      hl[0] = (h0[0]&0xFFFFu) | (h0[1]<<16);
      hl[1] = (h0[2]&0xFFFFu) | (h0[3]<<16);
      hl[2] = (h1[0]&0xFFFFu) | (h1[1]<<16);
      hl[3] = (h1[2]&0xFFFFu) | (h1[3]<<16);
      bfrag ah = __builtin_bit_cast(bfrag, hh);
      bfrag al = __builtin_bit_cast(bfrag, hl);
      #pragma unroll
      for(int nt=0;nt<5;nt++){
        acc[nt] = MF(ah, W2H[nt], acc[nt]);
        acc[nt] = MF(ah, W2L[nt], acc[nt]);
        acc[nt] = MF(al, W2H[nt], acc[nt]);
      }
    }
    {
      unsigned short* dh = XH + srow*136 + sseg*32;
      unsigned short* dl = XL + srow*136 + sseg*32;
      #pragma unroll
      for(int c=0;c<4;c++){
        u32x4 hi, lo;
        pack8(xs[2*c], xs[2*c+1], hi, lo);
        *(u32x4*)(dh + c*8) = hi;
        *(u32x4*)(dl + c*8) = lo;
      }
    }
    __syncthreads();

    // ---------- phase B: projection MFMAs (+ prefetch x_{t+1}) ----------
    if(t+1<SL){
      const float* p = x + ((long)(b0+srow)*SL + (t+1))*NI + sseg*32;
      #pragma unroll
      for(int i=0;i<8;i++) xs[i] = ((const float4*)p)[i];
    }
    {
      const unsigned short* arow = XH + (w*16+lr)*136 + lg*8;
      const unsigned short* brow = XL + (w*16+lr)*136 + lg*8;
      #pragma unroll
      for(int ks=0;ks<4;ks++){
        bfrag ah = *(const bfrag*)(arow + ks*32);
        bfrag al = *(const bfrag*)(brow + ks*32);
        #pragma unroll
        for(int nt=0;nt<5;nt++){
          const int p = nt*4+ks;
          bfrag bl = *(const bfrag*)(WLp + p*256 + lane*4);
          acc[nt] = MF(ah, WHF[p], acc[nt]);   // xh*Wh
          acc[nt] = MF(ah, bl,     acc[nt]);   // xh*Wl
          acc[nt] = MF(al, WHF[p], acc[nt]);   // xl*Wh
        }
      }
    }
    #pragma unroll
    for(int nt=0;nt<5;nt++){
      #pragma unroll
      for(int i=0;i<4;i++)
        XP[(w*16+lg*4+i)*88 + colp[nt]] = (_Float16)acc[nt][i];
    }
    __syncthreads();

    // ---------- phase C: fp32 gate math ----------
    {
      float hv[5];
      #pragma unroll
      for(int u=0;u<5;u++){
        f16x4 v = *(const f16x4*)(XP + srow*88 + (sseg*5+u)*4);
        float ig = sigf((float)v[0]);
        float fg = sigf((float)v[1]);
        float gg = tanhf2((float)v[2]);
        float og = sigf((float)v[3]);
        cst[u] = fg*cst[u] + ig*gg;
        hv[u]  = og * tanhf2(cst[u]);
      }
      if(t==SL-1){
        #pragma unroll
        for(int u=0;u<5;u++) out[(long)(b0+srow)*40 + sseg*5+u] = hv[u];
        // stage W_ih_b (bf16-hi frags) into WL region (dead after B(9))
        #pragma unroll
        for(int q=0;q<5;q++){
          int G = q*256 + tid;
          int p = G>>6, l = G&63;
          int g = (p>>2)*16 + (l&15), k0 = (p&3)*32 + ((l>>4)*8);
          const float* src = Wih_b + g*NI + k0;
          float4 a = *(const float4*)src;
          float4 b = *(const float4*)(src+4);
          u32x4 hi;
          pack8hi(a,b,hi);
          *(u32x4*)(WLp + p*256 + l*4) = hi;
        }
      } else {
        #pragma unroll
        for(int u=0;u<5;u++){
          float h = hv[u];
          u32 hh16 = fb(h)>>16;
          float hlf = h - hi32(h);
          u32 hl16 = fb(hlf)>>16;
          HB[srow*36 + sseg*5+u] = (hh16<<16) | hl16;
        }
      }
    }
    __syncthreads();
  }

  // ---------- backward direction: single step, h0=c0=0, reuses x tile t=9 ----------
  {
    float biasb[5];
    #pragma unroll
    for(int nt=0;nt<5;nt++) biasb[nt] = bih_b[nt*16+lr] + bhh_b[nt*16+lr];
    #pragma unroll
    for(int nt=0;nt<5;nt++){ f32x4 v={biasb[nt],biasb[nt],biasb[nt],biasb[nt]}; acc[nt]=v; }
    const unsigned short* arow = XH + (w*16+lr)*136 + lg*8;
    const unsigned short* brow = XL + (w*16+lr)*136 + lg*8;
    #pragma unroll
    for(int ks=0;ks<4;ks++){
      bfrag ah = *(const bfrag*)(arow + ks*32);
      bfrag al = *(const bfrag*)(brow + ks*32);
      #pragma unroll
      for(int nt=0;nt<5;nt++){
        const int p = nt*4+ks;
        bfrag bh_ = *(const bfrag*)(WLp + p*256 + lane*4);
        acc[nt] = MF(ah, bh_, acc[nt]);
        acc[nt] = MF(al, bh_, acc[nt]);
      }
    }
    #pragma unroll
    for(int nt=0;nt<5;nt++){
      #pragma unroll
      for(int i=0;i<4;i++)
        XP[(w*16+lg*4+i)*88 + colp[nt]] = (_Float16)acc[nt][i];
    }
    __syncthreads();
    #pragma unroll
    for(int u=0;u<5;u++){
      f16x4 v = *(const f16x4*)(XP + srow*88 + (sseg*5+u)*4);
      float ig = sigf((float)v[0]);
      float gg = tanhf2((float)v[2]);
      float og = sigf((float)v[3]);
      float cb = ig*gg;                 // c = f*0 + i*g
      out[(long)(b0+srow)*40 + 20 + sseg*5+u] = og * tanhf2(cb);
    }
  }
}

extern "C" void kernel_launch(void* const* d_in, const int* in_sizes, int n_in,
                              void* d_out, int out_size, void* d_ws, size_t ws_size,
                              hipStream_t stream) {
  const float* x     = (const float*)d_in[0];
  const float* Wih_f = (const float*)d_in[1];
  const float* Whh_f = (const float*)d_in[2];
  const float* bih_f = (const float*)d_in[3];
  const float* bhh_f = (const float*)d_in[4];
  const float* Wih_b = (const float*)d_in[5];
  // d_in[6] = W_hh_b: provably unused (hs_b[0] has h0 = 0)
  const float* bih_b = (const float*)d_in[7];
  const float* bhh_b = (const float*)d_in[8];
  float* out = (float*)d_out;
  bilstm_kernel<<<dim3(512), dim3(256), 0, stream>>>(
      x, Wih_f, Whh_f, bih_f, bhh_f, Wih_b, bih_b, bhh_b, out);
}

// Round 2
// 63.604 us; speedup vs baseline: 1.1313x; 1.1313x over previous
//
#include <hip/hip_runtime.h>

#define SL 10
#define NI 128

typedef float f32x4 __attribute__((ext_vector_type(4)));
typedef unsigned int u32;
typedef u32 u32x4 __attribute__((ext_vector_type(4)));
typedef __bf16 bfrag __attribute__((ext_vector_type(8)));   // 8 bf16 = 4 VGPR MFMA frag

__device__ __forceinline__ u32 fb(float f){ return __float_as_uint(f); }
__device__ __forceinline__ float hi32(float f){ return __uint_as_float(fb(f)&0xFFFF0000u); }

// D = A*B + C ; A indexed by output row m, B by output col n
__device__ __forceinline__ f32x4 MF(bfrag a, bfrag b, f32x4 c){
  return __builtin_amdgcn_mfma_f32_16x16x32_bf16(a, b, c, 0, 0, 0);
}

__device__ __forceinline__ float sigf(float x){ return __fdividef(1.f, 1.f + __expf(-x)); }
__device__ __forceinline__ float tanhf2(float x){ return __fdividef(2.f, 1.f + __expf(-2.f*x)) - 1.f; }

// split 8 fp32 -> bf16-hi (truncated) and bf16-lo (residual) packed as 4 u32 each
__device__ __forceinline__ void pack8(float4 a, float4 b, u32x4& hi, u32x4& lo){
  float f[8] = {a.x,a.y,a.z,a.w,b.x,b.y,b.z,b.w};
  #pragma unroll
  for(int j=0;j<4;j++){
    float p=f[2*j], q=f[2*j+1];
    hi[j] = (fb(p)>>16) | (fb(q)&0xFFFF0000u);
    float pr = p - hi32(p), qr = q - hi32(q);
    lo[j] = (fb(pr)>>16) | (fb(qr)&0xFFFF0000u);
  }
}
__device__ __forceinline__ void pack8hi(float4 a, float4 b, u32x4& hi){
  float f[8] = {a.x,a.y,a.z,a.w,b.x,b.y,b.z,b.w};
  #pragma unroll
  for(int j=0;j<4;j++)
    hi[j] = (fb(f[2*j])>>16) | (fb(f[2*j+1])&0xFFFF0000u);
}

// Transposed-MFMA bidirectional LSTM.
//   A = weights (gate-permuted rows), B = x / h (col = batch), C: row=gate, col=batch.
//   Gate-row permutation: tile nt, frag row m -> original gate g = (m&3)*20 + nt*4 + (m>>2),
//   so C rows lg*4+i hold gate types i={i,f,g,o} of unit u = nt*4+lg  -> gate math in-register.
// LDS (bytes):
//   XH [64][136] bf16 : 0     .. 17408  (x hi-split, row stride 272B)
//   XL [64][136] bf16 : 17408 .. 34816  (x lo-split)
//   WL [20 frags][64 lanes][16B] : 34816 .. 55296 (W_ih_f lo frags; reused for W_ih_b hi)
//   HB [64][36] u32   : 55296 .. 64512  (h packed (hh16<<16)|hl16, k-pad zeroed)
__global__ __launch_bounds__(256, 2) void bilstm_kernel(
    const float* __restrict__ x,
    const float* __restrict__ Wih_f, const float* __restrict__ Whh_f,
    const float* __restrict__ bih_f, const float* __restrict__ bhh_f,
    const float* __restrict__ Wih_b,
    const float* __restrict__ bih_b, const float* __restrict__ bhh_b,
    float* __restrict__ out)
{
  __shared__ __attribute__((aligned(16))) u32 smem[16128]; // 64512 B

  unsigned short* XH = (unsigned short*)smem;
  unsigned short* XL = XH + 64*136;
  u32*            WLp = smem + 8704;    // 34816/4
  u32*            HB  = smem + 13824;   // 55296/4

  const int tid  = threadIdx.x;
  const int lane = tid & 63;
  const int w    = tid >> 6;     // wave id: batch sub-tile (16 cols)
  const int lr   = lane & 15;    // frag row (A) / col (B) index
  const int lg   = lane >> 4;    // k-group
  const int b0   = blockIdx.x << 6;
  const int srow = tid >> 2;     // staging row (0..63)
  const int sseg = tid & 3;      // staging segment
  const int gbase = (lr&3)*20 + (lr>>2);   // permuted gate row: g = gbase + nt*4

  for(int i=tid;i<64*36;i+=256) HB[i]=0;   // zero h-buf incl. k-padding

  // ---- W_ih_f frags (A-operand): hi in regs, lo staged to LDS ----
  bfrag WHF[20];
  #pragma unroll
  for(int p=0;p<20;p++){
    const int nt=p>>2, ks=p&3;
    const float* src = Wih_f + (gbase + nt*4)*NI + ks*32 + lg*8;
    float4 a = *(const float4*)src;
    float4 b = *(const float4*)(src+4);
    u32x4 hi, lo;
    pack8(a,b,hi,lo);
    WHF[p] = __builtin_bit_cast(bfrag, hi);
    if(w == (p&3)) *(u32x4*)(WLp + p*256 + lane*4) = lo;
  }

  // ---- W_hh_f frags (K=20 zero-padded to 32), 2-level split, in regs ----
  bfrag W2H[5], W2L[5];
  #pragma unroll
  for(int nt=0;nt<5;nt++){
    u32x4 hi, lo;
    #pragma unroll
    for(int j=0;j<4;j++){
      const int k0 = lg*8 + 2*j;
      float p = (k0   < 20) ? Whh_f[(gbase+nt*4)*20 + k0  ] : 0.f;
      float q = (k0+1 < 20) ? Whh_f[(gbase+nt*4)*20 + k0+1] : 0.f;
      hi[j] = (fb(p)>>16) | (fb(q)&0xFFFF0000u);
      float pr = p - hi32(p), qr = q - hi32(q);
      lo[j] = (fb(pr)>>16) | (fb(qr)&0xFFFF0000u);
    }
    W2H[nt] = __builtin_bit_cast(bfrag, hi);
    W2L[nt] = __builtin_bit_cast(bfrag, lo);
  }

  // bias per lane: biasv[nt][ty] for unit u=nt*4+lg
  f32x4 biasv[5];
  #pragma unroll
  for(int nt=0;nt<5;nt++){
    const int u = nt*4+lg;
    f32x4 v;
    #pragma unroll
    for(int ty=0;ty<4;ty++) v[ty] = bih_f[ty*20+u] + bhh_f[ty*20+u];
    biasv[nt]=v;
  }

  // prefetch x tile t=0 into regs
  float4 xs[8];
  {
    const float* p = x + ((long)(b0+srow)*SL)*NI + sseg*32;
    #pragma unroll
    for(int i=0;i<8;i++) xs[i] = ((const float4*)p)[i];
  }

  float cst[5] = {0.f,0.f,0.f,0.f,0.f};
  f32x4 acc[5];

  __syncthreads();

  for(int t=0;t<SL;t++){
    // ---- stage x_t from prefetch regs ----
    {
      unsigned short* dh = XH + srow*136 + sseg*32;
      unsigned short* dl = XL + srow*136 + sseg*32;
      #pragma unroll
      for(int c=0;c<4;c++){
        u32x4 hi, lo;
        pack8(xs[2*c], xs[2*c+1], hi, lo);
        *(u32x4*)(dh + c*8) = hi;
        *(u32x4*)(dl + c*8) = lo;
      }
    }
    __syncthreads();

    // prefetch x_{t+1}
    if(t+1<SL){
      const float* p = x + ((long)(b0+srow)*SL + (t+1))*NI + sseg*32;
      #pragma unroll
      for(int i=0;i<8;i++) xs[i] = ((const float4*)p)[i];
    }

    // h_{t-1} LDS read issued early
    u32x4 h0, h1;
    if(t>0){
      const u32* hp = HB + (w*16+lr)*36 + lg*8;
      h0 = *(const u32x4*)hp;
      h1 = *(const u32x4*)(hp+4);
    }

    #pragma unroll
    for(int nt=0;nt<5;nt++) acc[nt] = biasv[nt];

    // ---- projection: 60 MFMAs (3-term split) ----
    {
      const unsigned short* xrh = XH + (w*16+lr)*136;
      const unsigned short* xrl = XL + (w*16+lr)*136;
      #pragma unroll
      for(int ks=0;ks<4;ks++){
        bfrag bxh = *(const bfrag*)(xrh + ks*32 + lg*8);
        bfrag bxl = *(const bfrag*)(xrl + ks*32 + lg*8);
        #pragma unroll
        for(int nt=0;nt<5;nt++){
          const int p = nt*4+ks;
          bfrag wl = *(const bfrag*)(WLp + p*256 + lane*4);
          acc[nt] = MF(WHF[p], bxh, acc[nt]);   // Wh*xh
          acc[nt] = MF(wl,     bxh, acc[nt]);   // Wl*xh
          acc[nt] = MF(WHF[p], bxl, acc[nt]);   // Wh*xl
        }
      }
    }

    // ---- recurrence: 15 MFMAs ----
    if(t>0){
      u32x4 hh, hl;
      hh[0] = (h0[0]>>16) | (h0[1]&0xFFFF0000u);
      hh[1] = (h0[2]>>16) | (h0[3]&0xFFFF0000u);
      hh[2] = (h1[0]>>16) | (h1[1]&0xFFFF0000u);
      hh[3] = (h1[2]>>16) | (h1[3]&0xFFFF0000u);
      hl[0] = (h0[0]&0xFFFFu) | (h0[1]<<16);
      hl[1] = (h0[2]&0xFFFFu) | (h0[3]<<16);
      hl[2] = (h1[0]&0xFFFFu) | (h1[1]<<16);
      hl[3] = (h1[2]&0xFFFFu) | (h1[3]<<16);
      bfrag bhh = __builtin_bit_cast(bfrag, hh);
      bfrag bhl = __builtin_bit_cast(bfrag, hl);
      #pragma unroll
      for(int nt=0;nt<5;nt++){
        acc[nt] = MF(W2H[nt], bhh, acc[nt]);
        acc[nt] = MF(W2L[nt], bhh, acc[nt]);
        acc[nt] = MF(W2H[nt], bhl, acc[nt]);
      }
    }

    // ---- gate math fully in-register (fp32) ----
    #pragma unroll
    for(int nt=0;nt<5;nt++){
      float ig = sigf(acc[nt][0]);
      float fg = sigf(acc[nt][1]);
      float gg = tanhf2(acc[nt][2]);
      float og = sigf(acc[nt][3]);
      cst[nt] = fg*cst[nt] + ig*gg;
      float hv = og * tanhf2(cst[nt]);
      if(t==SL-1){
        out[(long)(b0+w*16+lr)*40 + nt*4+lg] = hv;
      } else {
        u32 hh16 = fb(hv)>>16;
        float hlf = hv - hi32(hv);
        HB[(w*16+lr)*36 + nt*4+lg] = (hh16<<16) | (fb(hlf)>>16);
      }
    }
    __syncthreads();
  }

  // ---- stage W_ih_b hi frags into WL (WL reads all done before last barrier) ----
  #pragma unroll
  for(int q=0;q<5;q++){
    const int G = q*256 + tid;
    const int p = G>>6, l = G&63;
    const int m = l&15, lgq = l>>4;
    const int g = (m&3)*20 + (p>>2)*4 + (m>>2);
    const float* src = Wih_b + g*NI + (p&3)*32 + lgq*8;
    float4 a = *(const float4*)src;
    float4 b = *(const float4*)(src+4);
    u32x4 hi;
    pack8hi(a,b,hi);
    *(u32x4*)(WLp + p*256 + l*4) = hi;
  }
  __syncthreads();

  // ---- backward direction: single step, h0=c0=0, reuses x tile t=9 ----
  {
    f32x4 acc2[5];
    #pragma unroll
    for(int nt=0;nt<5;nt++){
      const int u = nt*4+lg;
      f32x4 v;
      #pragma unroll
      for(int ty=0;ty<4;ty++) v[ty] = bih_b[ty*20+u] + bhh_b[ty*20+u];
      acc2[nt]=v;
    }
    const unsigned short* xrh = XH + (w*16+lr)*136;
    const unsigned short* xrl = XL + (w*16+lr)*136;
    #pragma unroll
    for(int ks=0;ks<4;ks++){
      bfrag bxh = *(const bfrag*)(xrh + ks*32 + lg*8);
      bfrag bxl = *(const bfrag*)(xrl + ks*32 + lg*8);
      #pragma unroll
      for(int nt=0;nt<5;nt++){
        const int p = nt*4+ks;
        bfrag wb = *(const bfrag*)(WLp + p*256 + lane*4);
        acc2[nt] = MF(wb, bxh, acc2[nt]);
        acc2[nt] = MF(wb, bxl, acc2[nt]);
      }
    }
    #pragma unroll
    for(int nt=0;nt<5;nt++){
      float ig = sigf(acc2[nt][0]);
      float gg = tanhf2(acc2[nt][2]);
      float og = sigf(acc2[nt][3]);
      float cb = ig*gg;                 // c = f*0 + i*g
      out[(long)(b0+w*16+lr)*40 + 20 + nt*4+lg] = og * tanhf2(cb);
    }
  }
}

extern "C" void kernel_launch(void* const* d_in, const int* in_sizes, int n_in,
                              void* d_out, int out_size, void* d_ws, size_t ws_size,
                              hipStream_t stream) {
  const float* x     = (const float*)d_in[0];
  const float* Wih_f = (const float*)d_in[1];
  const float* Whh_f = (const float*)d_in[2];
  const float* bih_f = (const float*)d_in[3];
  const float* bhh_f = (const float*)d_in[4];
  const float* Wih_b = (const float*)d_in[5];
  // d_in[6] = W_hh_b: provably unused (hs_b[0] has h0 = 0)
  const float* bih_b = (const float*)d_in[7];
  const float* bhh_b = (const float*)d_in[8];
  float* out = (float*)d_out;
  bilstm_kernel<<<dim3(512), dim3(256), 0, stream>>>(
      x, Wih_f, Whh_f, bih_f, bhh_f, Wih_b, bih_b, bhh_b, out);
}

// Round 3
// 52.639 us; speedup vs baseline: 1.3669x; 1.2083x over previous
//
#include <hip/hip_runtime.h>

#define SL 10
#define NI 128

typedef float f32x4 __attribute__((ext_vector_type(4)));
typedef unsigned int u32;
typedef u32 u32x4 __attribute__((ext_vector_type(4)));
typedef _Float16 h8 __attribute__((ext_vector_type(8)));

__device__ __forceinline__ f32x4 MFH(h8 a, h8 b, f32x4 c){
  return __builtin_amdgcn_mfma_f32_16x16x32_f16(a, b, c, 0, 0, 0);
}
__device__ __forceinline__ float sigf(float x){ return __fdividef(1.f, 1.f + __expf(-x)); }
__device__ __forceinline__ float tanhf2(float x){ return __fdividef(2.f, 1.f + __expf(-2.f*x)) - 1.f; }

__device__ __forceinline__ h8 to_h8(float4 a, float4 b){
  h8 r;
  r[0]=(_Float16)a.x; r[1]=(_Float16)a.y; r[2]=(_Float16)a.z; r[3]=(_Float16)a.w;
  r[4]=(_Float16)b.x; r[5]=(_Float16)b.y; r[6]=(_Float16)b.z; r[7]=(_Float16)b.w;
  return r;
}

// One wave (64 threads) per 16 batch rows. Zero barriers.
//   A = weights (gate-permuted rows), B = x/h fragments loaded straight from
//   global / rebuilt from a 2KB wave-private LDS h-buffer (wave-coherent, no
//   s_barrier). f16 operands: x 1-term, W_ih 1-term, h 2-term, W_hh 1-term.
//   Gate permutation: A-row lr -> gate g=(lr&3)*20+(lr>>2)+nt*4, so C-reg i of
//   lane (lr,lg) = gate type i of unit u=nt*4+lg, col lr -> in-register gates.
__global__ __launch_bounds__(64, 2) void bilstm_kernel(
    const float* __restrict__ x,
    const float* __restrict__ Wih_f, const float* __restrict__ Whh_f,
    const float* __restrict__ bih_f, const float* __restrict__ bhh_f,
    const float* __restrict__ Wih_b,
    const float* __restrict__ bih_b, const float* __restrict__ bhh_b,
    float* __restrict__ out)
{
  __shared__ u32 HB[16*33];   // [col lr][unit u] = (h_hi16<<16)|h_lo16, stride 33 vs banks
  const int lane = threadIdx.x;
  const int lr = lane & 15;
  const int lg = lane >> 4;
  const long row = (long)blockIdx.x*16 + lr;
  const int gb = (lr&3)*20 + (lr>>2);

  for(int i=lane;i<16*33;i+=64) HB[i]=0;   // zero pads (u>=20, lg=3 range)

  // ---- W_ih_f fragments (f16), register-resident ----
  h8 WIH[20];
  #pragma unroll
  for(int p=0;p<20;p++){
    const int nt=p>>2, ks=p&3;
    const float* s = Wih_f + (gb+nt*4)*NI + ks*32 + lg*8;
    WIH[p] = to_h8(*(const float4*)s, *(const float4*)(s+4));
  }
  // ---- W_hh_f fragments (K=20 zero-padded to 32) ----
  h8 WHH[5];
  #pragma unroll
  for(int nt=0;nt<5;nt++){
    h8 r;
    #pragma unroll
    for(int j=0;j<8;j++){
      const int k = lg*8+j;
      r[j] = (_Float16)((k<20) ? Whh_f[(gb+nt*4)*20+k] : 0.f);
    }
    WHH[nt]=r;
  }
  f32x4 biasv[5];
  #pragma unroll
  for(int nt=0;nt<5;nt++)
    #pragma unroll
    for(int ty=0;ty<4;ty++)
      biasv[nt][ty] = bih_f[ty*20+nt*4+lg] + bhh_f[ty*20+nt*4+lg];

  // ---- x fragment loads straight from global (coalesced 128B per row) ----
  const float* xbase = x + row*(SL*NI) + lg*8;
  float4 xa[4], xb4[4];
  #pragma unroll
  for(int ks=0;ks<4;ks++){
    xa[ks]  = *(const float4*)(xbase + ks*32);
    xb4[ks] = *(const float4*)(xbase + ks*32 + 4);
  }

  float cst[5]={0.f,0.f,0.f,0.f,0.f};
  h8 bx[4];          // current-t B fragments (live after loop for bwd @ t=9)
  f32x4 acc[5];

  #pragma unroll
  for(int t=0;t<SL;t++){
    #pragma unroll
    for(int ks=0;ks<4;ks++) bx[ks]=to_h8(xa[ks],xb4[ks]);
    if(t+1<SL){   // prefetch next timestep
      #pragma unroll
      for(int ks=0;ks<4;ks++){
        xa[ks]  = *(const float4*)(xbase + (t+1)*NI + ks*32);
        xb4[ks] = *(const float4*)(xbase + (t+1)*NI + ks*32 + 4);
      }
    }
    u32x4 hb0, hb1;
    if(t>0){      // h_{t-1} fragment source (wave-coherent LDS, no barrier)
      const u32* hp = HB + lr*33 + lg*8;
      hb0=*(const u32x4*)hp; hb1=*(const u32x4*)(hp+4);
    }
    #pragma unroll
    for(int nt=0;nt<5;nt++) acc[nt]=biasv[nt];
    // projection: 20 MFMAs
    #pragma unroll
    for(int ks=0;ks<4;ks++)
      #pragma unroll
      for(int nt=0;nt<5;nt++)
        acc[nt]=MFH(WIH[nt*4+ks], bx[ks], acc[nt]);
    // recurrence: 10 MFMAs (h 2-term)
    if(t>0){
      u32x4 hh, hl;
      hh[0]=(hb0[0]>>16)|(hb0[1]&0xffff0000u);
      hh[1]=(hb0[2]>>16)|(hb0[3]&0xffff0000u);
      hh[2]=(hb1[0]>>16)|(hb1[1]&0xffff0000u);
      hh[3]=(hb1[2]>>16)|(hb1[3]&0xffff0000u);
      hl[0]=(hb0[0]&0xffffu)|(hb0[1]<<16);
      hl[1]=(hb0[2]&0xffffu)|(hb0[3]<<16);
      hl[2]=(hb1[0]&0xffffu)|(hb1[1]<<16);
      hl[3]=(hb1[2]&0xffffu)|(hb1[3]<<16);
      h8 fh=__builtin_bit_cast(h8,hh), fl=__builtin_bit_cast(h8,hl);
      #pragma unroll
      for(int nt=0;nt<5;nt++){
        acc[nt]=MFH(WHH[nt], fh, acc[nt]);
        acc[nt]=MFH(WHH[nt], fl, acc[nt]);
      }
    }
    // in-register fp32 gate math
    #pragma unroll
    for(int nt=0;nt<5;nt++){
      float ig=sigf(acc[nt][0]);
      float fg=sigf(acc[nt][1]);
      float gg=tanhf2(acc[nt][2]);
      float og=sigf(acc[nt][3]);
      cst[nt]=fg*cst[nt]+ig*gg;
      float hv=og*tanhf2(cst[nt]);
      if(t==SL-1){
        out[row*40 + nt*4+lg] = hv;
      } else {
        _Float16 hh16=(_Float16)hv;
        _Float16 hl16=(_Float16)(hv-(float)hh16);
        HB[lr*33 + nt*4+lg] = ((u32)__builtin_bit_cast(unsigned short,hh16)<<16)
                              | (u32)__builtin_bit_cast(unsigned short,hl16);
      }
    }
  }

  // ---- backward direction: one step, h0=c0=0, reuses bx[] (= x at t=9) ----
  f32x4 acc2[5];
  #pragma unroll
  for(int nt=0;nt<5;nt++)
    #pragma unroll
    for(int ty=0;ty<4;ty++)
      acc2[nt][ty] = bih_b[ty*20+nt*4+lg] + bhh_b[ty*20+nt*4+lg];
  #pragma unroll
  for(int ks=0;ks<4;ks++){
    #pragma unroll
    for(int nt=0;nt<5;nt++){
      const float* s = Wih_b + (gb+nt*4)*NI + ks*32 + lg*8;
      acc2[nt]=MFH(to_h8(*(const float4*)s, *(const float4*)(s+4)), bx[ks], acc2[nt]);
    }
  }
  #pragma unroll
  for(int nt=0;nt<5;nt++){
    float ig=sigf(acc2[nt][0]);
    float gg=tanhf2(acc2[nt][2]);
    float og=sigf(acc2[nt][3]);
    out[row*40 + 20 + nt*4+lg] = og*tanhf2(ig*gg);   // c = i*g (f-gate hits c0=0)
  }
}

extern "C" void kernel_launch(void* const* d_in, const int* in_sizes, int n_in,
                              void* d_out, int out_size, void* d_ws, size_t ws_size,
                              hipStream_t stream) {
  const float* x     = (const float*)d_in[0];
  const float* Wih_f = (const float*)d_in[1];
  const float* Whh_f = (const float*)d_in[2];
  const float* bih_f = (const float*)d_in[3];
  const float* bhh_f = (const float*)d_in[4];
  const float* Wih_b = (const float*)d_in[5];
  // d_in[6] = W_hh_b: provably unused (hs_b[0] has h0 = 0)
  const float* bih_b = (const float*)d_in[7];
  const float* bhh_b = (const float*)d_in[8];
  float* out = (float*)d_out;
  bilstm_kernel<<<dim3(2048), dim3(64), 0, stream>>>(
      x, Wih_f, Whh_f, bih_f, bhh_f, Wih_b, bih_b, bhh_b, out);
}